// Round 3
// baseline (485.994 us; speedup 1.0000x reference)
//
#include <hip/hip_runtime.h>
#include <math.h>

#define TN 2048            // T
#define NF 4096            // Bluestein FFT length
#define NB 64              // batch
#define LF 6142LL          // L = 3T-2
#define L2F 12284LL        // 2L
#define PI_D 3.14159265358979323846264338327950288
#define C8 0.70710678118654752440084436210485
#define W16R1 0.92387953251128675613
#define W16I1 0.38268343236508977173

typedef double2 cpx;

__device__ __forceinline__ cpx cmk(double a, double b){ cpx r; r.x=a; r.y=b; return r; }
__device__ __forceinline__ cpx cadd(cpx a, cpx b){ return cmk(a.x+b.x, a.y+b.y); }
__device__ __forceinline__ cpx csub(cpx a, cpx b){ return cmk(a.x-b.x, a.y-b.y); }
__device__ __forceinline__ cpx cmul(cpx a, cpx b){ return cmk(a.x*b.x - a.y*b.y, a.x*b.y + a.y*b.x); }
__device__ __forceinline__ cpx cmulc(cpx a, cpx b){ return cmk(a.x*b.x + a.y*b.y, a.y*b.x - a.x*b.y); } // a*conj(b)

// LDS swizzle: optimal (8 consecutive lanes -> 8 distinct bank groups) for all
// radix-16/radix-8 stage strides used here (cpx granularity, involution)
__device__ __forceinline__ int SW(int i){ return i ^ ((i >> 4) & 7); }

__constant__ int R8c[8]  = {0,4,2,6,1,5,3,7};
__constant__ int R16c[16] = {0,8,4,12,2,10,6,14,1,9,5,13,3,11,7,15};

// ---------- 8-point register FFT (DIF, natural in; reg q holds freq R8[q])
__device__ __forceinline__ void fft8_bc(cpx* a){
  cpx u, v, d;
  u=a[0]; v=a[2]; a[0]=cadd(u,v); a[2]=csub(u,v);
  u=a[1]; v=a[3]; a[1]=cadd(u,v); d=csub(u,v); a[3]=cmk(d.y, -d.x);
  u=a[4]; v=a[6]; a[4]=cadd(u,v); a[6]=csub(u,v);
  u=a[5]; v=a[7]; a[5]=cadd(u,v); d=csub(u,v); a[7]=cmk(d.y, -d.x);
  u=a[0]; v=a[1]; a[0]=cadd(u,v); a[1]=csub(u,v);
  u=a[2]; v=a[3]; a[2]=cadd(u,v); a[3]=csub(u,v);
  u=a[4]; v=a[5]; a[4]=cadd(u,v); a[5]=csub(u,v);
  u=a[6]; v=a[7]; a[6]=cadd(u,v); a[7]=csub(u,v);
}
__device__ __forceinline__ void fft8(cpx* a){
  cpx u, v, d;
  u=a[0]; v=a[4]; a[0]=cadd(u,v); a[4]=csub(u,v);
  u=a[1]; v=a[5]; a[1]=cadd(u,v); d=csub(u,v); a[5]=cmk(C8*(d.x+d.y), C8*(d.y-d.x));
  u=a[2]; v=a[6]; a[2]=cadd(u,v); d=csub(u,v); a[6]=cmk(d.y, -d.x);
  u=a[3]; v=a[7]; a[3]=cadd(u,v); d=csub(u,v); a[7]=cmk(C8*(d.y-d.x), -C8*(d.x+d.y));
  fft8_bc(a);
}
// unscaled inverse (input in fft8 reg order, output natural, x8)
__device__ __forceinline__ void ifft8(cpx* a){
  cpx u, v, t;
  u=a[0]; v=a[1]; a[0]=cadd(u,v); a[1]=csub(u,v);
  u=a[2]; v=a[3]; a[2]=cadd(u,v); a[3]=csub(u,v);
  u=a[4]; v=a[5]; a[4]=cadd(u,v); a[5]=csub(u,v);
  u=a[6]; v=a[7]; a[6]=cadd(u,v); a[7]=csub(u,v);
  u=a[0]; v=a[2]; a[0]=cadd(u,v); a[2]=csub(u,v);
  u=a[1]; t=a[3]; v=cmk(-t.y, t.x); a[1]=cadd(u,v); a[3]=csub(u,v);
  u=a[4]; v=a[6]; a[4]=cadd(u,v); a[6]=csub(u,v);
  u=a[5]; t=a[7]; v=cmk(-t.y, t.x); a[5]=cadd(u,v); a[7]=csub(u,v);
  u=a[0]; v=a[4]; a[0]=cadd(u,v); a[4]=csub(u,v);
  u=a[1]; t=a[5]; v=cmk(C8*(t.x-t.y), C8*(t.x+t.y)); a[1]=cadd(u,v); a[5]=csub(u,v);
  u=a[2]; t=a[6]; v=cmk(-t.y, t.x); a[2]=cadd(u,v); a[6]=csub(u,v);
  u=a[3]; t=a[7]; v=cmk(-C8*(t.x+t.y), C8*(t.x-t.y)); a[3]=cadd(u,v); a[7]=csub(u,v);
}
// ---------- 16-point register FFT: reg q holds freq R16[q] = brev4(q)
__device__ __forceinline__ void fft16(cpx* a){
  cpx u, v, d;
  u=a[0]; v=a[8];  a[0]=cadd(u,v); a[8]=csub(u,v);
  u=a[1]; v=a[9];  a[1]=cadd(u,v); d=csub(u,v); a[9] =cmul(d, cmk(W16R1,-W16I1));
  u=a[2]; v=a[10]; a[2]=cadd(u,v); d=csub(u,v); a[10]=cmk(C8*(d.x+d.y), C8*(d.y-d.x));
  u=a[3]; v=a[11]; a[3]=cadd(u,v); d=csub(u,v); a[11]=cmul(d, cmk(W16I1,-W16R1));
  u=a[4]; v=a[12]; a[4]=cadd(u,v); d=csub(u,v); a[12]=cmk(d.y,-d.x);
  u=a[5]; v=a[13]; a[5]=cadd(u,v); d=csub(u,v); a[13]=cmul(d, cmk(-W16I1,-W16R1));
  u=a[6]; v=a[14]; a[6]=cadd(u,v); d=csub(u,v); a[14]=cmk(C8*(d.y-d.x), -C8*(d.x+d.y));
  u=a[7]; v=a[15]; a[7]=cadd(u,v); d=csub(u,v); a[15]=cmul(d, cmk(-W16R1,-W16I1));
  fft8(a); fft8(a+8);
}
// zero top half input (t>=8): a[0..7] = x, computes full fft16
__device__ __forceinline__ void fft16z(cpx* a){
  a[8]  = a[0];
  a[9]  = cmul(a[1], cmk(W16R1,-W16I1));
  a[10] = cmk(C8*(a[2].x+a[2].y), C8*(a[2].y-a[2].x));
  a[11] = cmul(a[3], cmk(W16I1,-W16R1));
  a[12] = cmk(a[4].y, -a[4].x);
  a[13] = cmul(a[5], cmk(-W16I1,-W16R1));
  a[14] = cmk(C8*(a[6].y-a[6].x), -C8*(a[6].x+a[6].y));
  a[15] = cmul(a[7], cmk(-W16R1,-W16I1));
  fft8(a); fft8(a+8);
}
// unscaled inverse (input in fft16 reg order, output natural, x16)
__device__ __forceinline__ void ifft16(cpx* a){
  ifft8(a); ifft8(a+8);
  cpx t, bv;
  t=a[0]; bv=a[8];                               a[0]=cadd(t,bv); a[8] =csub(t,bv);
  t=a[1]; bv=cmulc(a[9],  cmk(W16R1,-W16I1));   a[1]=cadd(t,bv); a[9] =csub(t,bv);
  t=a[2]; bv=cmk(C8*(a[10].x-a[10].y), C8*(a[10].x+a[10].y)); a[2]=cadd(t,bv); a[10]=csub(t,bv);
  t=a[3]; bv=cmulc(a[11], cmk(W16I1,-W16R1));   a[3]=cadd(t,bv); a[11]=csub(t,bv);
  t=a[4]; bv=cmk(-a[12].y, a[12].x);             a[4]=cadd(t,bv); a[12]=csub(t,bv);
  t=a[5]; bv=cmulc(a[13], cmk(-W16I1,-W16R1));  a[5]=cadd(t,bv); a[13]=csub(t,bv);
  t=a[6]; bv=cmk(-C8*(a[14].x+a[14].y), C8*(a[14].x-a[14].y)); a[6]=cadd(t,bv); a[14]=csub(t,bv);
  t=a[7]; bv=cmulc(a[15], cmk(-W16R1,-W16I1));  a[7]=cadd(t,bv); a[15]=csub(t,bv);
}

// ---------- K1: filters + tables
__global__ __launch_bounds__(256) void k_prep(
    const float* fw1, const float* fb1, const float* fw2, const float* fb2,
    const float* gw1, const float* gb1, const float* gw2, const float* gb2,
    const float* pw1, const float* pb1, const float* pw2, const float* pb2,
    const float* qw1, const float* qb1, const float* qw2, const float* qb2,
    double* arr, cpx* tw, cpx* Q, cpx* g2)
{
  int gid = blockIdx.x * 256 + threadIdx.x;   // < 8192
  if (gid < 4096){
    double s, c;
    sincos(-2.0 * PI_D * (double)gid / 4096.0, &s, &c);
    tw[gid] = cmk(c, s);
  }
  if (gid < 2048){
    long long i = gid;
    double s, c;
    long long a = ((2LL * TN - 2) * i) % LF;
    long long b = (i * i) % L2F;
    long long comb = (2 * a + b) % L2F;
    sincos(PI_D * (double)comb / (double)LF, &s, &c);
    Q[gid] = cmk(c, s);
    long long a2 = ((2LL * TN - 2 + i) * (TN - 1)) % LF;
    long long comb2 = (2 * a2 + b) % L2F;
    double phi = PI_D * (double)comb2 / (double)LF;
    double scale = 1.0 / ((double)LF * (double)LF) / (4096.0 * 4096.0);
    sincos(2.0 * phi, &s, &c);
    g2[gid] = cmk(c * scale, s * scale);
  }
  int fid = gid >> 11;
  int m = gid & (TN - 1);
  const float *W1, *B1, *W2, *B2;
  if (fid == 0){ W1=fw1; B1=fb1; W2=fw2; B2=fb2; }
  else if (fid == 1){ W1=gw1; B1=gb1; W2=gw2; B2=gb2; }
  else if (fid == 2){ W1=pw1; B1=pb1; W2=pw2; B2=pb2; }
  else { W1=qw1; B1=qb1; W2=qw2; B2=qb2; }
  int s = (fid == 0 || fid == 2) ? (TN - 1 - m) : m;
  double sv = (double)s;
  double z = (double)B2[0];
  #pragma unroll
  for (int h = 0; h < 5; h++)
    z += (double)W2[h] * tanh(sv * (double)W1[h] + (double)B1[h]);
  arr[fid * TN + m] = z * exp(-5.0 * sv);
}

// ---------- SO(3) helpers
__device__ __forceinline__ void mat_mul3(double* D, const double* A, const double* B){
  double r[9];
  #pragma unroll
  for (int i = 0; i < 3; i++)
    #pragma unroll
    for (int j = 0; j < 3; j++)
      r[i*3+j] = A[i*3]*B[j] + A[i*3+1]*B[3+j] + A[i*3+2]*B[6+j];
  #pragma unroll
  for (int k = 0; k < 9; k++) D[k] = r[k];
}
__device__ __forceinline__ void rod3(double* M, const double* a1, const double* a2,
                                     double z1, double z2){
  double G[9];
  #pragma unroll
  for (int k = 0; k < 9; k++) G[k] = a1[k]*z1 + a2[k]*z2;
  double wx = G[7], wy = G[2], wz = G[3];
  double th2 = wx*wx + wy*wy + wz*wz;
  double sa, cb;
  if (th2 < 1e-12){ sa = 1.0 - th2/6.0; cb = 0.5 - th2/24.0; }
  else { double th = sqrt(th2); sa = sin(th)/th; cb = (1.0 - cos(th))/th2; }
  double w[3] = {wx, wy, wz};
  #pragma unroll
  for (int i = 0; i < 3; i++)
    #pragma unroll
    for (int j = 0; j < 3; j++){
      double v = sa * G[i*3+j] + cb * (w[i]*w[j]);
      if (i == j) v += 1.0 - cb * th2;
      M[i*3+j] = v;
    }
}

// ---------- K2 merged: blocks 0-255 = H spectra (xQ folded), 256-319 = SO(3) scan, 320 = chat
__global__ __launch_bounds__(256) void k_front(
    const float* x, const float* A1f, const float* A2f,
    const double* arr, const cpx* Q, const cpx* tw,
    cpx* HsQ, double* Asc, cpx* chat)
{
  __shared__ double smem[8192];   // 64 KB union
  int tid = threadIdx.x;
  int bid = blockIdx.x;
  if (bid < 256){
    cpx* part = (cpx*)smem;
    int f = bid >> 6;
    int jbase = (bid & 63) * 32;
    int chunk = tid & 7;
    int jl = tid >> 3;
    long long j = jbase + jl;
    long long jj = j + TN - 1;
    double s, c;
    sincos(-2.0 * PI_D * (double)jj / (double)LF, &s, &c);
    cpx W = cmk(c, s);
    long long m0 = (long long)chunk * 256;
    long long p0 = ((m0 + TN - 1) * jj) % LF;
    sincos(-2.0 * PI_D * (double)p0 / (double)LF, &s, &c);
    cpx ph = cmk(c, s);
    const double* a = arr + f * TN;
    cpx acc = cmk(0.0, 0.0);
    for (int m = (int)m0; m < (int)m0 + 256; m++){
      double av = a[m];
      acc.x += av * ph.x;
      acc.y += av * ph.y;
      ph = cmul(ph, W);
    }
    part[tid] = acc;
    __syncthreads();
    if (chunk == 0){
      cpx tot = cmk(0.0, 0.0);
      for (int q = 0; q < 8; q++) tot = cadd(tot, part[(jl << 3) + q]);
      HsQ[f * TN + (int)j] = cmul(tot, Q[j]);
    }
  } else if (bid < 320){
    int b = bid - 256;
    double (*S)[9] = (double(*)[9])smem;
    int k = tid;
    double a1[9], a2[9];
    #pragma unroll
    for (int i = 0; i < 3; i++)
      #pragma unroll
      for (int j = 0; j < 3; j++){
        a1[i*3+j] = (double)A1f[i*3+j] - (double)A1f[j*3+i];
        a2[i*3+j] = (double)A2f[i*3+j] - (double)A2f[j*3+i];
      }
    const float* xb = x + (size_t)b * TN * 2;
    double C[9] = {1,0,0, 0,1,0, 0,0,1};
    for (int i = 0; i < 8; i++){
      int t = k * 8 + i;
      if (t >= 1){
        double M[9];
        rod3(M, a1, a2, (double)xb[2*t], (double)xb[2*t+1]);
        mat_mul3(C, C, M);
      }
    }
    #pragma unroll
    for (int q = 0; q < 9; q++) S[k][q] = C[q];
    __syncthreads();
    for (int ofs = 1; ofs < 256; ofs <<= 1){
      double Lm[9], Rm[9];
      bool act = (k >= ofs);
      if (act){
        #pragma unroll
        for (int q = 0; q < 9; q++){ Lm[q] = S[k-ofs][q]; Rm[q] = S[k][q]; }
      }
      __syncthreads();
      if (act){
        double P[9];
        mat_mul3(P, Lm, Rm);
        #pragma unroll
        for (int q = 0; q < 9; q++) S[k][q] = P[q];
      }
      __syncthreads();
    }
    double P[9];
    if (k == 0){
      P[0]=1; P[1]=0; P[2]=0; P[3]=0; P[4]=1; P[5]=0; P[6]=0; P[7]=0; P[8]=1;
    } else {
      #pragma unroll
      for (int q = 0; q < 9; q++) P[q] = S[k-1][q];
    }
    for (int i = 0; i < 8; i++){
      int t = k * 8 + i;
      if (t >= 1){
        double M[9];
        rod3(M, a1, a2, (double)xb[2*t], (double)xb[2*t+1]);
        mat_mul3(P, P, M);
      }
      #pragma unroll
      for (int q = 0; q < 9; q++)
        Asc[(((size_t)b * 9 + q) << 11) + t] = P[q];
    }
  } else {
    // ---- chat: radix-16^3 DIF of chirp; stored permuted: chat[(s&15)<<8 | s>>4]
    cpx* buf = (cpx*)smem;
    for (int m = tid; m < NF; m += 256){
      long long mm = (m <= 2048) ? m : (NF - m);
      long long qq = (mm * mm) % L2F;
      double s, c;
      sincos(-PI_D * (double)qq / (double)LF, &s, &c);
      buf[SW(m)] = cmk(c, s);
    }
    __syncthreads();
    {
      cpx a[16];
      #pragma unroll
      for (int j = 0; j < 16; j++) a[j] = buf[SW(tid + (j << 8))];
      fft16(a);
      #pragma unroll
      for (int q = 0; q < 16; q++){
        int k = R16c[q]; cpx v = a[q];
        if (k) v = cmul(v, tw[tid * k]);
        buf[SW(tid + (k << 8))] = v;
      }
    }
    __syncthreads();
    {
      int pos2 = tid & 15;
      int base = ((tid >> 4) << 8) | pos2;
      cpx a[16];
      #pragma unroll
      for (int j = 0; j < 16; j++) a[j] = buf[SW(base + (j << 4))];
      fft16(a);
      #pragma unroll
      for (int q = 0; q < 16; q++){
        int k = R16c[q]; cpx v = a[q];
        if (k) v = cmul(v, tw[(pos2 * k) << 4]);
        buf[SW(base + (k << 4))] = v;
      }
    }
    __syncthreads();
    {
      int base = tid << 4;
      cpx a[16];
      #pragma unroll
      for (int j = 0; j < 16; j++) a[j] = buf[SW(base + j)];
      fft16(a);
      #pragma unroll
      for (int q = 0; q < 16; q++) buf[SW(base + R16c[q])] = a[q];
    }
    __syncthreads();
    for (int i = tid; i < NF; i += 256)
      chat[((i & 15) << 8) | (i >> 4)] = buf[SW(i)];
  }
}

// ---------- K3: 2048-pt FFT (radix 8,16,16), two channels per block -> U natural order
__global__ __launch_bounds__(256, 2) void k_fft_u(const double* Asc, const cpx* tw, cpx* U){
  __shared__ cpx buf[NF];
  int tid = threadIdx.x;
  int b = blockIdx.x / 5, p = blockIdx.x % 5;
  int c0 = 2 * p;
  bool has1 = (2 * p + 1) < 9;
  int c1 = has1 ? (2 * p + 1) : 8;
  const double* s0 = Asc + (((size_t)b * 9 + c0) << 11);
  const double* s1 = Asc + (((size_t)b * 9 + c1) << 11);
  for (int t = tid; t < TN; t += 256){
    buf[SW(t)] = cmk(s0[t], 0.0);
    buf[SW(t + TN)] = cmk(s1[t], 0.0);
  }
  __syncthreads();
  // S1: radix-8, stride 256 (per channel)
  #pragma unroll
  for (int it = 0; it < 2; it++){
    int cb = it << 11;
    cpx a[8];
    #pragma unroll
    for (int j = 0; j < 8; j++) a[j] = buf[SW(cb + tid + (j << 8))];
    fft8(a);
    #pragma unroll
    for (int q = 0; q < 8; q++){
      int k = R8c[q]; cpx v = a[q];
      if (k) v = cmul(v, tw[(tid * k) << 1]);
      buf[SW(cb + tid + (k << 8))] = v;
    }
  }
  __syncthreads();
  // S2: radix-16, stride 16
  {
    int ch = tid >> 7, i2 = tid & 127;
    int pos2 = i2 & 15;
    int base = (ch << 11) + (((i2 >> 4) << 8) | pos2);
    cpx a[16];
    #pragma unroll
    for (int j = 0; j < 16; j++) a[j] = buf[SW(base + (j << 4))];
    fft16(a);
    #pragma unroll
    for (int q = 0; q < 16; q++){
      int k = R16c[q]; cpx v = a[q];
      if (k) v = cmul(v, tw[(pos2 * k) << 4]);
      buf[SW(base + (k << 4))] = v;
    }
  }
  __syncthreads();
  // S3: radix-16, stride 1
  {
    int ch = tid >> 7, i3 = tid & 127;
    int base = (ch << 11) + (i3 << 4);
    cpx a[16];
    #pragma unroll
    for (int j = 0; j < 16; j++) a[j] = buf[SW(base + j)];
    fft16(a);
    #pragma unroll
    for (int q = 0; q < 16; q++) buf[SW(base + R16c[q])] = a[q];
  }
  __syncthreads();
  // unscramble -> natural order, coalesced global write
  size_t u0 = (((size_t)b * 9 + c0) << 11);
  size_t u1 = (((size_t)b * 9 + c1) << 11);
  #pragma unroll
  for (int ii = 0; ii < 8; ii++){
    int f = tid + (ii << 8);
    int s = ((f & 7) << 8) + (((f >> 3) & 15) << 4) + (f >> 7);
    U[u0 + f] = buf[SW(s)];
    if (has1) U[u1 + f] = buf[SW(TN + s)];
  }
}

// ---------- K4: main CZT. radix-16^3 Bluestein, 5 phases/pass, 4 passes.
__global__ __launch_bounds__(256, 2) void k_main(const cpx* U, const cpx* HsQ, const cpx* tw,
                                                 const cpx* chat, const cpx* g2, float* Sst){
  int bc = blockIdx.x;
  int b = bc / 9, c = bc % 9;
  int ct = (c % 3) * 3 + (c / 3);        // inv(A) = A^T for SO(3)
  const cpx* Uc  = U + ((size_t)b * 9 + c)  * TN;
  const cpx* Uct = U + ((size_t)b * 9 + ct) * TN;
  __shared__ cpx buf[NF];
  int pos = threadIdx.x;
  int pos2 = pos & 15;
  int base2 = ((pos >> 4) << 8) | pos2;
  int base3 = pos << 4;
  cpx pst[8], acc[8];
  #pragma unroll
  for (int j = 0; j < 8; j++) acc[j] = cmk(0.0, 0.0);

  for (int p = 0; p < 4; p++){           // AA, AB, BA, BB
    const cpx* Us = (p & 1) ? Uc : Uct;
    const cpx* H = HsQ + (p << 11);
    __syncthreads();                     // buf free (prev pass invS1 done)
    cpx a[16];
    // S1: staging fused, top half zero (radix-16, stride 256)
    #pragma unroll
    for (int t = 0; t < 8; t++){
      int j = pos + (t << 8);
      a[t] = cmul(Us[j], H[j]);
    }
    fft16z(a);
    #pragma unroll
    for (int q = 0; q < 16; q++){
      int k = R16c[q]; cpx v = a[q];
      if (k) v = cmul(v, tw[pos * k]);
      buf[SW(pos + (k << 8))] = v;
    }
    __syncthreads();
    // S2 fwd (stride 16)
    #pragma unroll
    for (int j = 0; j < 16; j++) a[j] = buf[SW(base2 + (j << 4))];
    fft16(a);
    #pragma unroll
    for (int q = 0; q < 16; q++){
      int k = R16c[q]; cpx v = a[q];
      if (k) v = cmul(v, tw[(pos2 * k) << 4]);
      buf[SW(base2 + (k << 4))] = v;
    }
    __syncthreads();
    // S3 + chat + invS3 fused in registers (stride 1, pos=0 -> no twiddles)
    #pragma unroll
    for (int j = 0; j < 16; j++) a[j] = buf[SW(base3 + j)];
    fft16(a);
    #pragma unroll
    for (int q = 0; q < 16; q++) a[q] = cmul(a[q], chat[(R16c[q] << 8) | pos]);
    ifft16(a);
    #pragma unroll
    for (int j = 0; j < 16; j++) buf[SW(base3 + j)] = a[j];
    __syncthreads();
    // invS2
    #pragma unroll
    for (int q = 0; q < 16; q++){
      int k = R16c[q];
      cpx v = buf[SW(base2 + (k << 4))];
      a[q] = k ? cmulc(v, tw[(pos2 * k) << 4]) : v;
    }
    ifft16(a);
    #pragma unroll
    for (int j = 0; j < 16; j++) buf[SW(base2 + (j << 4))] = a[j];
    __syncthreads();
    // invS1: outputs r = pos + 256j, keep j<8, accumulate in registers
    #pragma unroll
    for (int q = 0; q < 16; q++){
      int k = R16c[q];
      cpx v = buf[SW(pos + (k << 8))];
      a[q] = k ? cmulc(v, tw[pos * k]) : v;
    }
    ifft16(a);
    #pragma unroll
    for (int j = 0; j < 8; j++){
      if ((p & 1) == 0) pst[j] = a[j];
      else acc[j] = cadd(acc[j], cmul(pst[j], a[j]));
    }
  }
  #pragma unroll
  for (int j = 0; j < 8; j++){
    int r = pos + (j << 8);
    cpx g = g2[r];
    Sst[((size_t)bc << 11) + r] = (float)(acc[j].x * g.x - acc[j].y * g.y);
  }
}

// ---------- K5: transpose [b][c][r] -> out[b][r][c] (coalesced both sides via LDS)
__global__ __launch_bounds__(256) void k_out(const float* Sst, float* out){
  __shared__ float ld[9][513];
  int b = blockIdx.x >> 2;
  int r0 = (blockIdx.x & 3) << 9;
  for (int idx = threadIdx.x; idx < 9 * 512; idx += 256){
    int cc = idx >> 9, r = idx & 511;
    ld[cc][r] = Sst[(((size_t)b * 9 + cc) << 11) + r0 + r];
  }
  __syncthreads();
  for (int idx = threadIdx.x; idx < 512 * 9; idx += 256){
    int r = idx / 9, cc = idx - 9 * r;
    out[((size_t)b * TN + r0 + r) * 9 + cc] = ld[cc][r];
  }
}

extern "C" void kernel_launch(void* const* d_in, const int* in_sizes, int n_in,
                              void* d_out, int out_size, void* d_ws, size_t ws_size,
                              hipStream_t stream){
  const float* x  = (const float*)d_in[0];
  const float* A1 = (const float*)d_in[1];
  const float* A2 = (const float*)d_in[2];
  const float* fpar[16];
  for (int i = 0; i < 16; i++) fpar[i] = (const float*)d_in[3 + i];
  float* out = (float*)d_out;

  // workspace carve (units: doubles), total ~28.7 MB
  double* ws = (double*)d_ws;
  size_t o = 0;
  double* arr  = ws + o;         o += 4 * TN;
  cpx* HsQ     = (cpx*)(ws + o); o += 2 * 4 * TN;
  cpx* tw      = (cpx*)(ws + o); o += 2 * NF;
  cpx* chat    = (cpx*)(ws + o); o += 2 * NF;
  cpx* Q       = (cpx*)(ws + o); o += 2 * TN;
  cpx* g2      = (cpx*)(ws + o); o += 2 * TN;
  double* Asc  = ws + o;         o += (size_t)NB * TN * 9;      // 9.4 MB
  cpx* U       = (cpx*)(ws + o); o += 2 * (size_t)NB * 9 * TN;  // 18.9 MB
  float* Sst   = (float*)Asc;    // Asc dead after k_fft_u; alias for staging (4.7 MB)

  k_prep<<<32, 256, 0, stream>>>(fpar[0], fpar[1], fpar[2], fpar[3],
                                 fpar[4], fpar[5], fpar[6], fpar[7],
                                 fpar[8], fpar[9], fpar[10], fpar[11],
                                 fpar[12], fpar[13], fpar[14], fpar[15],
                                 arr, tw, Q, g2);
  k_front<<<321, 256, 0, stream>>>(x, A1, A2, arr, Q, tw, HsQ, Asc, chat);
  k_fft_u<<<NB * 5, 256, 0, stream>>>(Asc, tw, U);
  k_main<<<NB * 9, 256, 0, stream>>>(U, HsQ, tw, chat, g2, Sst);
  k_out<<<NB * 4, 256, 0, stream>>>(Sst, out);
}

// Round 4
// 251.628 us; speedup vs baseline: 1.9314x; 1.9314x over previous
//
#include <hip/hip_runtime.h>
#include <math.h>

#define TN 2048            // T
#define NF 4096            // Bluestein FFT length
#define NB 64              // batch
#define LF 6142LL          // L = 3T-2
#define L2F 12284LL        // 2L
#define PI_D 3.14159265358979323846264338327950288
#define C8 0.70710678118654752440084436210485
#define W16R1 0.92387953251128675613
#define W16I1 0.38268343236508977173

typedef double2 cpx;

__device__ __forceinline__ cpx cmk(double a, double b){ cpx r; r.x=a; r.y=b; return r; }
__device__ __forceinline__ cpx cadd(cpx a, cpx b){ return cmk(a.x+b.x, a.y+b.y); }
__device__ __forceinline__ cpx csub(cpx a, cpx b){ return cmk(a.x-b.x, a.y-b.y); }
__device__ __forceinline__ cpx cmul(cpx a, cpx b){ return cmk(a.x*b.x - a.y*b.y, a.x*b.y + a.y*b.x); }
__device__ __forceinline__ cpx cmulc(cpx a, cpx b){ return cmk(a.x*b.x + a.y*b.y, a.y*b.x - a.x*b.y); } // a*conj(b)

// LDS swizzle: 8 consecutive lanes -> 8 distinct bank groups for all strides used
__device__ __forceinline__ int SW(int i){ return i ^ ((i >> 4) & 7); }

// ---------- 8-point register FFT (DIF, natural in; reg q holds freq R8[q]={0,4,2,6,1,5,3,7})
__device__ __forceinline__ void fft8_bc(cpx* a){
  cpx u, v, d;
  u=a[0]; v=a[2]; a[0]=cadd(u,v); a[2]=csub(u,v);
  u=a[1]; v=a[3]; a[1]=cadd(u,v); d=csub(u,v); a[3]=cmk(d.y, -d.x);
  u=a[4]; v=a[6]; a[4]=cadd(u,v); a[6]=csub(u,v);
  u=a[5]; v=a[7]; a[5]=cadd(u,v); d=csub(u,v); a[7]=cmk(d.y, -d.x);
  u=a[0]; v=a[1]; a[0]=cadd(u,v); a[1]=csub(u,v);
  u=a[2]; v=a[3]; a[2]=cadd(u,v); a[3]=csub(u,v);
  u=a[4]; v=a[5]; a[4]=cadd(u,v); a[5]=csub(u,v);
  u=a[6]; v=a[7]; a[6]=cadd(u,v); a[7]=csub(u,v);
}
__device__ __forceinline__ void fft8(cpx* a){
  cpx u, v, d;
  u=a[0]; v=a[4]; a[0]=cadd(u,v); a[4]=csub(u,v);
  u=a[1]; v=a[5]; a[1]=cadd(u,v); d=csub(u,v); a[5]=cmk(C8*(d.x+d.y), C8*(d.y-d.x));
  u=a[2]; v=a[6]; a[2]=cadd(u,v); d=csub(u,v); a[6]=cmk(d.y, -d.x);
  u=a[3]; v=a[7]; a[3]=cadd(u,v); d=csub(u,v); a[7]=cmk(C8*(d.y-d.x), -C8*(d.x+d.y));
  fft8_bc(a);
}
// unscaled inverse (input in fft8 reg order, output natural, x8)
__device__ __forceinline__ void ifft8(cpx* a){
  cpx u, v, t;
  u=a[0]; v=a[1]; a[0]=cadd(u,v); a[1]=csub(u,v);
  u=a[2]; v=a[3]; a[2]=cadd(u,v); a[3]=csub(u,v);
  u=a[4]; v=a[5]; a[4]=cadd(u,v); a[5]=csub(u,v);
  u=a[6]; v=a[7]; a[6]=cadd(u,v); a[7]=csub(u,v);
  u=a[0]; v=a[2]; a[0]=cadd(u,v); a[2]=csub(u,v);
  u=a[1]; t=a[3]; v=cmk(-t.y, t.x); a[1]=cadd(u,v); a[3]=csub(u,v);
  u=a[4]; v=a[6]; a[4]=cadd(u,v); a[6]=csub(u,v);
  u=a[5]; t=a[7]; v=cmk(-t.y, t.x); a[5]=cadd(u,v); a[7]=csub(u,v);
  u=a[0]; v=a[4]; a[0]=cadd(u,v); a[4]=csub(u,v);
  u=a[1]; t=a[5]; v=cmk(C8*(t.x-t.y), C8*(t.x+t.y)); a[1]=cadd(u,v); a[5]=csub(u,v);
  u=a[2]; t=a[6]; v=cmk(-t.y, t.x); a[2]=cadd(u,v); a[6]=csub(u,v);
  u=a[3]; t=a[7]; v=cmk(-C8*(t.x+t.y), C8*(t.x-t.y)); a[3]=cadd(u,v); a[7]=csub(u,v);
}
// ---------- 16-point register FFT: reg q holds freq R16[q] = brev4(q)
__device__ __forceinline__ void fft16(cpx* a){
  cpx u, v, d;
  u=a[0]; v=a[8];  a[0]=cadd(u,v); a[8]=csub(u,v);
  u=a[1]; v=a[9];  a[1]=cadd(u,v); d=csub(u,v); a[9] =cmul(d, cmk(W16R1,-W16I1));
  u=a[2]; v=a[10]; a[2]=cadd(u,v); d=csub(u,v); a[10]=cmk(C8*(d.x+d.y), C8*(d.y-d.x));
  u=a[3]; v=a[11]; a[3]=cadd(u,v); d=csub(u,v); a[11]=cmul(d, cmk(W16I1,-W16R1));
  u=a[4]; v=a[12]; a[4]=cadd(u,v); d=csub(u,v); a[12]=cmk(d.y,-d.x);
  u=a[5]; v=a[13]; a[5]=cadd(u,v); d=csub(u,v); a[13]=cmul(d, cmk(-W16I1,-W16R1));
  u=a[6]; v=a[14]; a[6]=cadd(u,v); d=csub(u,v); a[14]=cmk(C8*(d.y-d.x), -C8*(d.x+d.y));
  u=a[7]; v=a[15]; a[7]=cadd(u,v); d=csub(u,v); a[15]=cmul(d, cmk(-W16R1,-W16I1));
  fft8(a); fft8(a+8);
}
// zero top half input (t>=8): a[0..7] = x, computes full fft16
__device__ __forceinline__ void fft16z(cpx* a){
  a[8]  = a[0];
  a[9]  = cmul(a[1], cmk(W16R1,-W16I1));
  a[10] = cmk(C8*(a[2].x+a[2].y), C8*(a[2].y-a[2].x));
  a[11] = cmul(a[3], cmk(W16I1,-W16R1));
  a[12] = cmk(a[4].y, -a[4].x);
  a[13] = cmul(a[5], cmk(-W16I1,-W16R1));
  a[14] = cmk(C8*(a[6].y-a[6].x), -C8*(a[6].x+a[6].y));
  a[15] = cmul(a[7], cmk(-W16R1,-W16I1));
  fft8(a); fft8(a+8);
}
// unscaled inverse (input in fft16 reg order, output natural, x16)
__device__ __forceinline__ void ifft16(cpx* a){
  ifft8(a); ifft8(a+8);
  cpx t, bv;
  t=a[0]; bv=a[8];                               a[0]=cadd(t,bv); a[8] =csub(t,bv);
  t=a[1]; bv=cmulc(a[9],  cmk(W16R1,-W16I1));   a[1]=cadd(t,bv); a[9] =csub(t,bv);
  t=a[2]; bv=cmk(C8*(a[10].x-a[10].y), C8*(a[10].x+a[10].y)); a[2]=cadd(t,bv); a[10]=csub(t,bv);
  t=a[3]; bv=cmulc(a[11], cmk(W16I1,-W16R1));   a[3]=cadd(t,bv); a[11]=csub(t,bv);
  t=a[4]; bv=cmk(-a[12].y, a[12].x);             a[4]=cadd(t,bv); a[12]=csub(t,bv);
  t=a[5]; bv=cmulc(a[13], cmk(-W16I1,-W16R1));  a[5]=cadd(t,bv); a[13]=csub(t,bv);
  t=a[6]; bv=cmk(-C8*(a[14].x+a[14].y), C8*(a[14].x-a[14].y)); a[6]=cadd(t,bv); a[14]=csub(t,bv);
  t=a[7]; bv=cmulc(a[15], cmk(-W16R1,-W16I1));  a[7]=cadd(t,bv); a[15]=csub(t,bv);
}

// ---------- K1: filters + tables
__global__ __launch_bounds__(256) void k_prep(
    const float* fw1, const float* fb1, const float* fw2, const float* fb2,
    const float* gw1, const float* gb1, const float* gw2, const float* gb2,
    const float* pw1, const float* pb1, const float* pw2, const float* pb2,
    const float* qw1, const float* qb1, const float* qw2, const float* qb2,
    double* arr, cpx* tw, cpx* Q, cpx* g2)
{
  int gid = blockIdx.x * 256 + threadIdx.x;   // < 8192
  if (gid < 4096){
    double s, c;
    sincos(-2.0 * PI_D * (double)gid / 4096.0, &s, &c);
    tw[gid] = cmk(c, s);
  }
  if (gid < 2048){
    long long i = gid;
    double s, c;
    long long a = ((2LL * TN - 2) * i) % LF;
    long long b = (i * i) % L2F;
    long long comb = (2 * a + b) % L2F;
    sincos(PI_D * (double)comb / (double)LF, &s, &c);
    Q[gid] = cmk(c, s);
    long long a2 = ((2LL * TN - 2 + i) * (TN - 1)) % LF;
    long long comb2 = (2 * a2 + b) % L2F;
    double phi = PI_D * (double)comb2 / (double)LF;
    double scale = 1.0 / ((double)LF * (double)LF) / (4096.0 * 4096.0);
    sincos(2.0 * phi, &s, &c);
    g2[gid] = cmk(c * scale, s * scale);
  }
  int fid = gid >> 11;
  int m = gid & (TN - 1);
  const float *W1, *B1, *W2, *B2;
  if (fid == 0){ W1=fw1; B1=fb1; W2=fw2; B2=fb2; }
  else if (fid == 1){ W1=gw1; B1=gb1; W2=gw2; B2=gb2; }
  else if (fid == 2){ W1=pw1; B1=pb1; W2=pw2; B2=pb2; }
  else { W1=qw1; B1=qb1; W2=qw2; B2=qb2; }
  int s = (fid == 0 || fid == 2) ? (TN - 1 - m) : m;
  double sv = (double)s;
  double z = (double)B2[0];
  #pragma unroll
  for (int h = 0; h < 5; h++)
    z += (double)W2[h] * tanh(sv * (double)W1[h] + (double)B1[h]);
  arr[fid * TN + m] = z * exp(-5.0 * sv);
}

// ---------- SO(3) helpers
__device__ __forceinline__ void mat_mul3(double* D, const double* A, const double* B){
  double r[9];
  #pragma unroll
  for (int i = 0; i < 3; i++)
    #pragma unroll
    for (int j = 0; j < 3; j++)
      r[i*3+j] = A[i*3]*B[j] + A[i*3+1]*B[3+j] + A[i*3+2]*B[6+j];
  #pragma unroll
  for (int k = 0; k < 9; k++) D[k] = r[k];
}
__device__ __forceinline__ void rod3(double* M, const double* a1, const double* a2,
                                     double z1, double z2){
  double G[9];
  #pragma unroll
  for (int k = 0; k < 9; k++) G[k] = a1[k]*z1 + a2[k]*z2;
  double wx = G[7], wy = G[2], wz = G[3];
  double th2 = wx*wx + wy*wy + wz*wz;
  double sa, cb;
  if (th2 < 1e-12){ sa = 1.0 - th2/6.0; cb = 0.5 - th2/24.0; }
  else { double th = sqrt(th2); sa = sin(th)/th; cb = (1.0 - cos(th))/th2; }
  double w[3] = {wx, wy, wz};
  #pragma unroll
  for (int i = 0; i < 3; i++)
    #pragma unroll
    for (int j = 0; j < 3; j++){
      double v = sa * G[i*3+j] + cb * (w[i]*w[j]);
      if (i == j) v += 1.0 - cb * th2;
      M[i*3+j] = v;
    }
}

// ---------- K2 merged: blocks 0-255 = H spectra (xQ folded), 256-319 = SO(3) scan, 320 = chat
__global__ __launch_bounds__(256) void k_front(
    const float* x, const float* A1f, const float* A2f,
    const double* arr, const cpx* Q, const cpx* tw,
    cpx* HsQ, double* Asc, cpx* chat)
{
  __shared__ double smem[8192];   // 64 KB union
  int tid = threadIdx.x;
  int bid = blockIdx.x;
  if (bid < 256){
    cpx* part = (cpx*)smem;
    int f = bid >> 6;
    int jbase = (bid & 63) * 32;
    int chunk = tid & 7;
    int jl = tid >> 3;
    long long j = jbase + jl;
    long long jj = j + TN - 1;
    double s, c;
    sincos(-2.0 * PI_D * (double)jj / (double)LF, &s, &c);
    cpx W = cmk(c, s);
    long long m0 = (long long)chunk * 256;
    long long p0 = ((m0 + TN - 1) * jj) % LF;
    sincos(-2.0 * PI_D * (double)p0 / (double)LF, &s, &c);
    cpx ph = cmk(c, s);
    const double* a = arr + f * TN;
    cpx acc = cmk(0.0, 0.0);
    for (int m = (int)m0; m < (int)m0 + 256; m++){
      double av = a[m];
      acc.x += av * ph.x;
      acc.y += av * ph.y;
      ph = cmul(ph, W);
    }
    part[tid] = acc;
    __syncthreads();
    if (chunk == 0){
      cpx tot = cmk(0.0, 0.0);
      for (int q = 0; q < 8; q++) tot = cadd(tot, part[(jl << 3) + q]);
      HsQ[f * TN + (int)j] = cmul(tot, Q[j]);
    }
  } else if (bid < 320){
    int b = bid - 256;
    double (*S)[9] = (double(*)[9])smem;
    int k = tid;
    double a1[9], a2[9];
    #pragma unroll
    for (int i = 0; i < 3; i++)
      #pragma unroll
      for (int j = 0; j < 3; j++){
        a1[i*3+j] = (double)A1f[i*3+j] - (double)A1f[j*3+i];
        a2[i*3+j] = (double)A2f[i*3+j] - (double)A2f[j*3+i];
      }
    const float* xb = x + (size_t)b * TN * 2;
    double C[9] = {1,0,0, 0,1,0, 0,0,1};
    for (int i = 0; i < 8; i++){
      int t = k * 8 + i;
      if (t >= 1){
        double M[9];
        rod3(M, a1, a2, (double)xb[2*t], (double)xb[2*t+1]);
        mat_mul3(C, C, M);
      }
    }
    #pragma unroll
    for (int q = 0; q < 9; q++) S[k][q] = C[q];
    __syncthreads();
    for (int ofs = 1; ofs < 256; ofs <<= 1){
      double Lm[9], Rm[9];
      bool act = (k >= ofs);
      if (act){
        #pragma unroll
        for (int q = 0; q < 9; q++){ Lm[q] = S[k-ofs][q]; Rm[q] = S[k][q]; }
      }
      __syncthreads();
      if (act){
        double P[9];
        mat_mul3(P, Lm, Rm);
        #pragma unroll
        for (int q = 0; q < 9; q++) S[k][q] = P[q];
      }
      __syncthreads();
    }
    double P[9];
    if (k == 0){
      P[0]=1; P[1]=0; P[2]=0; P[3]=0; P[4]=1; P[5]=0; P[6]=0; P[7]=0; P[8]=1;
    } else {
      #pragma unroll
      for (int q = 0; q < 9; q++) P[q] = S[k-1][q];
    }
    for (int i = 0; i < 8; i++){
      int t = k * 8 + i;
      if (t >= 1){
        double M[9];
        rod3(M, a1, a2, (double)xb[2*t], (double)xb[2*t+1]);
        mat_mul3(P, P, M);
      }
      #pragma unroll
      for (int q = 0; q < 9; q++)
        Asc[(((size_t)b * 9 + q) << 11) + t] = P[q];
    }
  } else {
    // ---- chat: radix-16^3 DIF of chirp; stored permuted: chat[(s&15)<<8 | s>>4]
    cpx* buf = (cpx*)smem;
    for (int m = tid; m < NF; m += 256){
      long long mm = (m <= 2048) ? m : (NF - m);
      long long qq = (mm * mm) % L2F;
      double s, c;
      sincos(-PI_D * (double)qq / (double)LF, &s, &c);
      buf[SW(m)] = cmk(c, s);
    }
    __syncthreads();
    {
      const int R16[16] = {0,8,4,12,2,10,6,14,1,9,5,13,3,11,7,15};
      cpx a[16];
      #pragma unroll
      for (int j = 0; j < 16; j++) a[j] = buf[SW(tid + (j << 8))];
      fft16(a);
      #pragma unroll
      for (int q = 0; q < 16; q++){
        int k = R16[q]; cpx v = a[q];
        if (k) v = cmul(v, tw[tid * k]);
        buf[SW(tid + (k << 8))] = v;
      }
    }
    __syncthreads();
    {
      const int R16[16] = {0,8,4,12,2,10,6,14,1,9,5,13,3,11,7,15};
      int pos2 = tid & 15;
      int base = ((tid >> 4) << 8) | pos2;
      cpx a[16];
      #pragma unroll
      for (int j = 0; j < 16; j++) a[j] = buf[SW(base + (j << 4))];
      fft16(a);
      #pragma unroll
      for (int q = 0; q < 16; q++){
        int k = R16[q]; cpx v = a[q];
        if (k) v = cmul(v, tw[(pos2 * k) << 4]);
        buf[SW(base + (k << 4))] = v;
      }
    }
    __syncthreads();
    {
      const int R16[16] = {0,8,4,12,2,10,6,14,1,9,5,13,3,11,7,15};
      int base = tid << 4;
      cpx a[16];
      #pragma unroll
      for (int j = 0; j < 16; j++) a[j] = buf[SW(base + j)];
      fft16(a);
      #pragma unroll
      for (int q = 0; q < 16; q++) buf[SW(base + R16[q])] = a[q];
    }
    __syncthreads();
    for (int i = tid; i < NF; i += 256)
      chat[((i & 15) << 8) | (i >> 4)] = buf[SW(i)];
  }
}

// ---------- K3: 2048-pt FFT (radix 8,16,16), two channels per block -> U natural order
__global__ __launch_bounds__(256, 2) void k_fft_u(const double* Asc, const cpx* tw, cpx* U){
  __shared__ cpx buf[NF];
  int tid = threadIdx.x;
  int b = blockIdx.x / 5, p = blockIdx.x % 5;
  int c0 = 2 * p;
  bool has1 = (2 * p + 1) < 9;
  int c1 = has1 ? (2 * p + 1) : 8;
  const double* s0 = Asc + (((size_t)b * 9 + c0) << 11);
  const double* s1 = Asc + (((size_t)b * 9 + c1) << 11);
  for (int t = tid; t < TN; t += 256){
    buf[SW(t)] = cmk(s0[t], 0.0);
    buf[SW(t + TN)] = cmk(s1[t], 0.0);
  }
  __syncthreads();
  // S1: radix-8, stride 256 (per channel)
  #pragma unroll
  for (int it = 0; it < 2; it++){
    const int R8[8] = {0,4,2,6,1,5,3,7};
    int cb = it << 11;
    cpx a[8];
    #pragma unroll
    for (int j = 0; j < 8; j++) a[j] = buf[SW(cb + tid + (j << 8))];
    fft8(a);
    #pragma unroll
    for (int q = 0; q < 8; q++){
      int k = R8[q]; cpx v = a[q];
      if (k) v = cmul(v, tw[(tid * k) << 1]);
      buf[SW(cb + tid + (k << 8))] = v;
    }
  }
  __syncthreads();
  // S2: radix-16, stride 16
  {
    const int R16[16] = {0,8,4,12,2,10,6,14,1,9,5,13,3,11,7,15};
    int ch = tid >> 7, i2 = tid & 127;
    int pos2 = i2 & 15;
    int base = (ch << 11) + (((i2 >> 4) << 8) | pos2);
    cpx a[16];
    #pragma unroll
    for (int j = 0; j < 16; j++) a[j] = buf[SW(base + (j << 4))];
    fft16(a);
    #pragma unroll
    for (int q = 0; q < 16; q++){
      int k = R16[q]; cpx v = a[q];
      if (k) v = cmul(v, tw[(pos2 * k) << 4]);
      buf[SW(base + (k << 4))] = v;
    }
  }
  __syncthreads();
  // S3: radix-16, stride 1
  {
    const int R16[16] = {0,8,4,12,2,10,6,14,1,9,5,13,3,11,7,15};
    int ch = tid >> 7, i3 = tid & 127;
    int base = (ch << 11) + (i3 << 4);
    cpx a[16];
    #pragma unroll
    for (int j = 0; j < 16; j++) a[j] = buf[SW(base + j)];
    fft16(a);
    #pragma unroll
    for (int q = 0; q < 16; q++) buf[SW(base + R16[q])] = a[q];
  }
  __syncthreads();
  // unscramble -> natural order, coalesced global write
  size_t u0 = (((size_t)b * 9 + c0) << 11);
  size_t u1 = (((size_t)b * 9 + c1) << 11);
  #pragma unroll
  for (int ii = 0; ii < 8; ii++){
    int f = tid + (ii << 8);
    int s = ((f & 7) << 8) + (((f >> 3) & 15) << 4) + (f >> 7);
    U[u0 + f] = buf[SW(s)];
    if (has1) U[u1 + f] = buf[SW(TN + s)];
  }
}

// ---------- K4: CZT pair kernel. Block = (bc, pair); does passes (2*pair, 2*pair+1),
// writes Re(P_even * P_odd * g2) as fp32 partial. grid = 1152.
__global__ __launch_bounds__(256, 2) void k_czt(const cpx* U, const cpx* HsQ, const cpx* tw,
                                                const cpx* chat, const cpx* g2, float* Rst){
  int gb = blockIdx.x;
  int pair = gb & 1;
  int bc = gb >> 1;
  int b = bc / 9, c = bc % 9;
  int ct = (c % 3) * 3 + (c / 3);        // inv(A) = A^T for SO(3)
  const cpx* Uc  = U + ((size_t)b * 9 + c)  * TN;
  const cpx* Uct = U + ((size_t)b * 9 + ct) * TN;
  __shared__ cpx buf[NF];
  int pos = threadIdx.x;
  int pos2 = pos & 15;
  int base2 = ((pos >> 4) << 8) | pos2;
  int base3 = pos << 4;
  cpx pst[8];

  #pragma unroll
  for (int e = 0; e < 2; e++){
    const cpx* Us = e ? Uc : Uct;
    const cpx* H = HsQ + (((pair << 1) | e) << 11);
    __syncthreads();                     // buf free (prev pass invS1 done)
    cpx a[16];
    // S1: staging fused, top half zero (radix-16, stride 256)
    #pragma unroll
    for (int t = 0; t < 8; t++){
      int j = pos + (t << 8);
      a[t] = cmul(Us[j], H[j]);
    }
    fft16z(a);
    {
      const int R16[16] = {0,8,4,12,2,10,6,14,1,9,5,13,3,11,7,15};
      #pragma unroll
      for (int q = 0; q < 16; q++){
        int k = R16[q]; cpx v = a[q];
        if (k) v = cmul(v, tw[pos * k]);
        buf[SW(pos + (k << 8))] = v;
      }
    }
    __syncthreads();
    // S2 fwd (stride 16)
    #pragma unroll
    for (int j = 0; j < 16; j++) a[j] = buf[SW(base2 + (j << 4))];
    fft16(a);
    {
      const int R16[16] = {0,8,4,12,2,10,6,14,1,9,5,13,3,11,7,15};
      #pragma unroll
      for (int q = 0; q < 16; q++){
        int k = R16[q]; cpx v = a[q];
        if (k) v = cmul(v, tw[(pos2 * k) << 4]);
        buf[SW(base2 + (k << 4))] = v;
      }
    }
    __syncthreads();
    // S3 + chat + invS3 fused in registers (stride 1, pos=0 -> no twiddles)
    #pragma unroll
    for (int j = 0; j < 16; j++) a[j] = buf[SW(base3 + j)];
    fft16(a);
    {
      const int R16[16] = {0,8,4,12,2,10,6,14,1,9,5,13,3,11,7,15};
      #pragma unroll
      for (int q = 0; q < 16; q++) a[q] = cmul(a[q], chat[(R16[q] << 8) | pos]);
    }
    ifft16(a);
    #pragma unroll
    for (int j = 0; j < 16; j++) buf[SW(base3 + j)] = a[j];
    __syncthreads();
    // invS2
    {
      const int R16[16] = {0,8,4,12,2,10,6,14,1,9,5,13,3,11,7,15};
      #pragma unroll
      for (int q = 0; q < 16; q++){
        int k = R16[q];
        cpx v = buf[SW(base2 + (k << 4))];
        a[q] = k ? cmulc(v, tw[(pos2 * k) << 4]) : v;
      }
    }
    ifft16(a);
    #pragma unroll
    for (int j = 0; j < 16; j++) buf[SW(base2 + (j << 4))] = a[j];
    __syncthreads();
    // invS1: outputs r = pos + 256j, keep j<8
    {
      const int R16[16] = {0,8,4,12,2,10,6,14,1,9,5,13,3,11,7,15};
      #pragma unroll
      for (int q = 0; q < 16; q++){
        int k = R16[q];
        cpx v = buf[SW(pos + (k << 8))];
        a[q] = k ? cmulc(v, tw[pos * k]) : v;
      }
    }
    ifft16(a);
    if (e == 0){
      #pragma unroll
      for (int j = 0; j < 8; j++) pst[j] = a[j];
    } else {
      #pragma unroll
      for (int j = 0; j < 8; j++){
        int r = pos + (j << 8);
        cpx pr = cmul(pst[j], a[j]);
        cpx g = g2[r];
        Rst[((size_t)(pair * (NB * 9) + bc) << 11) + r] = (float)(pr.x * g.x - pr.y * g.y);
      }
    }
  }
}

// ---------- K5: combine pair partials + transpose [b][c][r] -> out[b][r][c]
__global__ __launch_bounds__(256) void k_out(const float* Rst, float* out){
  __shared__ float ld[9][513];
  int b = blockIdx.x >> 2;
  int r0 = (blockIdx.x & 3) << 9;
  for (int idx = threadIdx.x; idx < 9 * 512; idx += 256){
    int cc = idx >> 9, r = idx & 511;
    size_t o0 = ((size_t)(b * 9 + cc) << 11) + r0 + r;
    ld[cc][r] = Rst[o0] + Rst[o0 + ((size_t)(NB * 9) << 11)];
  }
  __syncthreads();
  for (int idx = threadIdx.x; idx < 512 * 9; idx += 256){
    int r = idx / 9, cc = idx - 9 * r;
    out[((size_t)b * TN + r0 + r) * 9 + cc] = ld[cc][r];
  }
}

extern "C" void kernel_launch(void* const* d_in, const int* in_sizes, int n_in,
                              void* d_out, int out_size, void* d_ws, size_t ws_size,
                              hipStream_t stream){
  const float* x  = (const float*)d_in[0];
  const float* A1 = (const float*)d_in[1];
  const float* A2 = (const float*)d_in[2];
  const float* fpar[16];
  for (int i = 0; i < 16; i++) fpar[i] = (const float*)d_in[3 + i];
  float* out = (float*)d_out;

  // workspace carve (units: doubles), total ~28.7 MB
  double* ws = (double*)d_ws;
  size_t o = 0;
  double* arr  = ws + o;         o += 4 * TN;
  cpx* HsQ     = (cpx*)(ws + o); o += 2 * 4 * TN;
  cpx* tw      = (cpx*)(ws + o); o += 2 * NF;
  cpx* chat    = (cpx*)(ws + o); o += 2 * NF;
  cpx* Q       = (cpx*)(ws + o); o += 2 * TN;
  cpx* g2      = (cpx*)(ws + o); o += 2 * TN;
  double* Asc  = ws + o;         o += (size_t)NB * TN * 9;      // 9.4 MB
  cpx* U       = (cpx*)(ws + o); o += 2 * (size_t)NB * 9 * TN;  // 18.9 MB
  float* Rst   = (float*)Asc;    // Asc dead after k_fft_u; 2*576*2048*4B = 9.4 MB exact fit

  k_prep<<<32, 256, 0, stream>>>(fpar[0], fpar[1], fpar[2], fpar[3],
                                 fpar[4], fpar[5], fpar[6], fpar[7],
                                 fpar[8], fpar[9], fpar[10], fpar[11],
                                 fpar[12], fpar[13], fpar[14], fpar[15],
                                 arr, tw, Q, g2);
  k_front<<<321, 256, 0, stream>>>(x, A1, A2, arr, Q, tw, HsQ, Asc, chat);
  k_fft_u<<<NB * 5, 256, 0, stream>>>(Asc, tw, U);
  k_czt<<<NB * 9 * 2, 256, 0, stream>>>(U, HsQ, tw, chat, g2, Rst);
  k_out<<<NB * 4, 256, 0, stream>>>(Rst, out);
}